// Round 3
// baseline (307.845 us; speedup 1.0000x reference)
//
#include <hip/hip_runtime.h>
#include <hip/hip_bf16.h>

constexpr int B = 2, L = 1024, D = 256, K = 64;
constexpr int N = B * L;      // 2048 rows total
constexpr int ROWS = 8;       // rows per block for row-wise kernels

// ---------------------------------------------------------------------------
// Encoder: for each row (b,l): xa = x + pos[l]; h = gelu(xa@w1+b1);
// phase = tanh(h@w2+b2)*pi; amp = softplus(xa@wa+ba)+0.1;
// pr = amp*cos(phase), pim = amp*sin(phase)   (each [N,K] fp32 in ws)
__global__ __launch_bounds__(256) void enc_kernel(
    const float* __restrict__ x, const float* __restrict__ pos,
    const float* __restrict__ w1, const float* __restrict__ b1,
    const float* __restrict__ w2, const float* __restrict__ b2,
    const float* __restrict__ wa, const float* __restrict__ ba,
    float* __restrict__ pr, float* __restrict__ pim) {
  __shared__ float xa[ROWS][D];
  __shared__ float h[ROWS][D];
  __shared__ float ph[ROWS][K];
  __shared__ float am[ROWS][K];
  const int tid = threadIdx.x;
  const int row0 = blockIdx.x * ROWS;

  for (int r = 0; r < ROWS; ++r) {
    const int row = row0 + r;
    const int l = row & (L - 1);
    xa[r][tid] = x[row * D + tid] + pos[l * D + tid];
  }
  __syncthreads();

  // h = gelu(xa @ w1 + b1): thread tid owns output column tid for all ROWS rows
  {
    float acc[ROWS];
    const float bb = b1[tid];
#pragma unroll
    for (int r = 0; r < ROWS; ++r) acc[r] = bb;
    for (int d = 0; d < D; ++d) {
      const float w = w1[d * D + tid];   // coalesced across lanes
#pragma unroll
      for (int r = 0; r < ROWS; ++r) acc[r] += xa[r][d] * w;  // LDS broadcast
    }
#pragma unroll
    for (int r = 0; r < ROWS; ++r) {
      const float v = acc[r];
      h[r][tid] = 0.5f * v * (1.0f + erff(v * 0.70710678f));  // exact gelu
    }
  }
  __syncthreads();

  // phase (threads 0..63) and amp (threads 64..127) in parallel
  if (tid < K) {
    const int j = tid;
    float acc[ROWS];
    const float bb = b2[j];
#pragma unroll
    for (int r = 0; r < ROWS; ++r) acc[r] = bb;
    for (int d = 0; d < D; ++d) {
      const float w = w2[d * K + j];
#pragma unroll
      for (int r = 0; r < ROWS; ++r) acc[r] += h[r][d] * w;
    }
#pragma unroll
    for (int r = 0; r < ROWS; ++r) ph[r][j] = tanhf(acc[r]) * 3.14159265358979f;
  } else if (tid < 2 * K) {
    const int j = tid - K;
    float acc[ROWS];
    const float bb = ba[j];
#pragma unroll
    for (int r = 0; r < ROWS; ++r) acc[r] = bb;
    for (int d = 0; d < D; ++d) {
      const float w = wa[d * K + j];
#pragma unroll
      for (int r = 0; r < ROWS; ++r) acc[r] += xa[r][d] * w;
    }
#pragma unroll
    for (int r = 0; r < ROWS; ++r) {
      const float v = acc[r];
      const float sp = fmaxf(v, 0.0f) + log1pf(expf(-fabsf(v)));  // stable softplus
      am[r][j] = sp + 0.1f;
    }
  }
  __syncthreads();

  for (int e = tid; e < ROWS * K; e += 256) {
    const int r = e >> 6, j = e & 63;
    const int row = row0 + r;
    const float a = am[r][j], p = ph[r][j];
    pr[row * K + j] = a * cosf(p);
    pim[row * K + j] = a * sinf(p);
  }
}

// ---------------------------------------------------------------------------
// V = x @ wv + bv   ([N,D] fp32 in ws)
__global__ __launch_bounds__(256) void v_kernel(
    const float* __restrict__ x, const float* __restrict__ wv,
    const float* __restrict__ bv, float* __restrict__ V) {
  __shared__ float xs[ROWS][D];
  const int tid = threadIdx.x;
  const int row0 = blockIdx.x * ROWS;
  for (int r = 0; r < ROWS; ++r) xs[r][tid] = x[(row0 + r) * D + tid];
  __syncthreads();
  float acc[ROWS];
  const float bb = bv[tid];
#pragma unroll
  for (int r = 0; r < ROWS; ++r) acc[r] = bb;
  for (int d = 0; d < D; ++d) {
    const float w = wv[d * D + tid];
#pragma unroll
    for (int r = 0; r < ROWS; ++r) acc[r] += xs[r][d] * w;
  }
#pragma unroll
  for (int r = 0; r < ROWS; ++r) V[(row0 + r) * D + tid] = acc[r];
}

// ---------------------------------------------------------------------------
// S[b, l, t] = sum_k qr[l,k]kr[t,k] + qi[l,k]ki[t,k], causal (t<=l), tiles 64x64.
// Grid enumerates (b, qt, kt) with kt<=qt: B * 136 blocks.
__global__ __launch_bounds__(256) void scores_kernel(
    const float* __restrict__ pr_q, const float* __restrict__ pi_q,
    const float* __restrict__ pr_k, const float* __restrict__ pi_k,
    float* __restrict__ S) {
  const int id = blockIdx.x;
  const int b = id / 136;
  const int rem = id % 136;
  int qt = 0;
  while ((qt + 1) * (qt + 2) / 2 <= rem) qt++;
  const int kt = rem - qt * (qt + 1) / 2;

  __shared__ float qr[64][68];  // pad keeps float4 alignment, breaks bank patterns
  __shared__ float qi[64][68];
  const int tid = threadIdx.x;
  const int qbase = b * L + qt * 64;
  const int kbase = b * L + kt * 64;

  for (int e = tid; e < 64 * 64; e += 256) {
    const int r = e >> 6, c = e & 63;
    qr[r][c] = pr_q[(qbase + r) * K + c];
    qi[r][c] = pi_q[(qbase + r) * K + c];
  }
  __syncthreads();

  const int t = tid & 63;
  const int q0 = tid >> 6;  // wave-uniform

  // K-row t into registers (L2-resident; each wave reloads, cheap)
  float krg[64], kig[64];
  {
    const float4* a4 = (const float4*)&pr_k[(kbase + t) * K];
    const float4* b4 = (const float4*)&pi_k[(kbase + t) * K];
#pragma unroll
    for (int g = 0; g < 16; ++g) {
      const float4 a = a4[g], bb = b4[g];
      krg[4 * g + 0] = a.x; krg[4 * g + 1] = a.y; krg[4 * g + 2] = a.z; krg[4 * g + 3] = a.w;
      kig[4 * g + 0] = bb.x; kig[4 * g + 1] = bb.y; kig[4 * g + 2] = bb.z; kig[4 * g + 3] = bb.w;
    }
  }

  float acc[16];
#pragma unroll
  for (int i = 0; i < 16; ++i) acc[i] = 0.0f;

#pragma unroll
  for (int g = 0; g < 16; ++g) {
#pragma unroll
    for (int i = 0; i < 16; ++i) {
      const int q = q0 + 4 * i;                       // wave-uniform -> broadcast reads
      const float4 a = *(const float4*)&qr[q][4 * g];
      const float4 c = *(const float4*)&qi[q][4 * g];
      acc[i] += a.x * krg[4 * g + 0] + a.y * krg[4 * g + 1] +
                a.z * krg[4 * g + 2] + a.w * krg[4 * g + 3] +
                c.x * kig[4 * g + 0] + c.y * kig[4 * g + 1] +
                c.z * kig[4 * g + 2] + c.w * kig[4 * g + 3];
    }
  }

#pragma unroll
  for (int i = 0; i < 16; ++i) {
    const int q = q0 + 4 * i;
    float v = acc[i];
    if (qt == kt && t > q) v = 0.0f;  // causal mask inside diagonal tile
    S[((size_t)(b * L + qt * 64 + q)) * L + kt * 64 + t] = v;
  }
}

// ---------------------------------------------------------------------------
// retrieved = S @ V (causal handled by S zeros + tile count).
// Grid: b(2) x q32-tile(32) x d64-chunk(4) = 256 blocks.
__global__ __launch_bounds__(256) void sv_kernel(
    const float* __restrict__ S, const float* __restrict__ V,
    float* __restrict__ ret) {
  const int id = blockIdx.x;
  const int jc = id & 3;
  const int qtile = (id >> 2) & 31;
  const int b = id >> 7;
  const int qbase = qtile * 32;
  const int ntile = (qbase + 31) / 64 + 1;

  __shared__ float Sl[32][68];
  const int tid = threadIdx.x;
  const int j0 = tid & 63;
  const int w = tid >> 6;  // wave-uniform

  float acc[8];
#pragma unroll
  for (int i = 0; i < 8; ++i) acc[i] = 0.0f;

  for (int tt = 0; tt < ntile; ++tt) {
    __syncthreads();
    for (int e = tid; e < 32 * 64; e += 256) {
      const int r = e >> 6, c = e & 63;
      Sl[r][c] = S[((size_t)(b * L + qbase + r)) * L + tt * 64 + c];
    }
    __syncthreads();

    float vreg[64];
    const float* Vp = &V[(b * L + tt * 64) * D + jc * 64 + j0];
#pragma unroll
    for (int t = 0; t < 64; ++t) vreg[t] = Vp[t * D];  // coalesced, L2-hot

#pragma unroll
    for (int g = 0; g < 16; ++g) {
#pragma unroll
      for (int i = 0; i < 8; ++i) {
        const int q = w + 4 * i;  // wave-uniform -> broadcast
        const float4 s4 = *(const float4*)&Sl[q][4 * g];
        acc[i] += s4.x * vreg[4 * g + 0] + s4.y * vreg[4 * g + 1] +
                  s4.z * vreg[4 * g + 2] + s4.w * vreg[4 * g + 3];
      }
    }
  }

#pragma unroll
  for (int i = 0; i < 8; ++i) {
    const int q = w + 4 * i;
    ret[(b * L + qbase + q) * D + jc * 64 + j0] = acc[i];
  }
}

// ---------------------------------------------------------------------------
// Epilogue: r = ret/sqrt((l+1)*K); layernorm; out = x + rn@wo + bo  (fp32 out)
__global__ __launch_bounds__(256) void epi_kernel(
    const float* __restrict__ ret, const float* __restrict__ x,
    const float* __restrict__ ln_g, const float* __restrict__ ln_b,
    const float* __restrict__ wo, const float* __restrict__ bo,
    float* __restrict__ out) {
  __shared__ float rn[ROWS][D];
  __shared__ float sums[ROWS][4];
  __shared__ float sqs[ROWS][4];
  const int tid = threadIdx.x;
  const int row0 = blockIdx.x * ROWS;
  const int w = tid >> 6;

  float val[ROWS];
#pragma unroll
  for (int r = 0; r < ROWS; ++r) {
    const int row = row0 + r;
    const int l = row & (L - 1);
    const float nrm = sqrtf((float)(l + 1) * 64.0f);
    val[r] = ret[row * D + tid] / nrm;
  }

#pragma unroll
  for (int r = 0; r < ROWS; ++r) {
    float v = val[r], v2 = v * v;
    for (int off = 32; off > 0; off >>= 1) {
      v += __shfl_xor(v, off, 64);
      v2 += __shfl_xor(v2, off, 64);
    }
    if ((tid & 63) == 0) { sums[r][w] = v; sqs[r][w] = v2; }
  }
  __syncthreads();

  const float g = ln_g[tid];
  const float bb = ln_b[tid];
#pragma unroll
  for (int r = 0; r < ROWS; ++r) {
    const float s = sums[r][0] + sums[r][1] + sums[r][2] + sums[r][3];
    const float sq = sqs[r][0] + sqs[r][1] + sqs[r][2] + sqs[r][3];
    const float mu = s * (1.0f / 256.0f);
    const float var = sq * (1.0f / 256.0f) - mu * mu;
    rn[r][tid] = (val[r] - mu) * rsqrtf(var + 1e-5f) * g + bb;
  }
  __syncthreads();

  float acc[ROWS];
  const float bo_ = bo[tid];
#pragma unroll
  for (int r = 0; r < ROWS; ++r) acc[r] = bo_;
  for (int d = 0; d < D; ++d) {
    const float wv = wo[d * D + tid];
#pragma unroll
    for (int r = 0; r < ROWS; ++r) acc[r] += rn[r][d] * wv;
  }
#pragma unroll
  for (int r = 0; r < ROWS; ++r) {
    const int row = row0 + r;
    out[row * D + tid] = x[row * D + tid] + acc[r];
  }
}

// ---------------------------------------------------------------------------
extern "C" void kernel_launch(void* const* d_in, const int* in_sizes, int n_in,
                              void* d_out, int out_size, void* d_ws, size_t ws_size,
                              hipStream_t stream) {
  (void)in_sizes; (void)n_in; (void)out_size; (void)ws_size;
  const float* x    = (const float*)d_in[0];
  const float* pos_k= (const float*)d_in[1];
  const float* w1_k = (const float*)d_in[2];
  const float* b1_k = (const float*)d_in[3];
  const float* w2_k = (const float*)d_in[4];
  const float* b2_k = (const float*)d_in[5];
  const float* wa_k = (const float*)d_in[6];
  const float* ba_k = (const float*)d_in[7];
  const float* pos_q= (const float*)d_in[8];
  const float* w1_q = (const float*)d_in[9];
  const float* b1_q = (const float*)d_in[10];
  const float* w2_q = (const float*)d_in[11];
  const float* b2_q = (const float*)d_in[12];
  const float* wa_q = (const float*)d_in[13];
  const float* ba_q = (const float*)d_in[14];
  const float* wv   = (const float*)d_in[15];
  const float* bv   = (const float*)d_in[16];
  const float* ln_g = (const float*)d_in[17];
  const float* ln_b = (const float*)d_in[18];
  const float* wo   = (const float*)d_in[19];
  const float* bo   = (const float*)d_in[20];

  float* ws = (float*)d_ws;
  float* kr = ws;                       // N*K
  float* ki = kr + (size_t)N * K;       // N*K
  float* qr = ki + (size_t)N * K;       // N*K
  float* qi = qr + (size_t)N * K;       // N*K
  float* V  = qi + (size_t)N * K;       // N*D
  float* S  = V + (size_t)N * D;        // B*L*L
  float* ret= S + (size_t)B * L * L;    // N*D

  enc_kernel<<<N / ROWS, 256, 0, stream>>>(x, pos_k, w1_k, b1_k, w2_k, b2_k, wa_k, ba_k, kr, ki);
  enc_kernel<<<N / ROWS, 256, 0, stream>>>(x, pos_q, w1_q, b1_q, w2_q, b2_q, wa_q, ba_q, qr, qi);
  v_kernel<<<N / ROWS, 256, 0, stream>>>(x, wv, bv, V);
  scores_kernel<<<B * 136, 256, 0, stream>>>(qr, qi, kr, ki, S);
  sv_kernel<<<256, 256, 0, stream>>>(S, V, ret);
  epi_kernel<<<N / ROWS, 256, 0, stream>>>(ret, x, ln_g, ln_b, wo, bo, (float*)d_out);
}

// Round 4
// 212.238 us; speedup vs baseline: 1.4505x; 1.4505x over previous
//
#include <hip/hip_runtime.h>
#include <hip/hip_bf16.h>

constexpr int B = 2, L = 1024, D = 256, K = 64;
constexpr int N = B * L;          // 2048 rows
constexpr int ROWS = 8;           // rows per block in encv
constexpr int NC = L / 64;        // 16 chunks of 64 tokens
constexpr int TM_CSTRIDE = 2 * K * D;         // 32768 floats per (b,c)
constexpr int TM_BSTRIDE = NC * TM_CSTRIDE;   // 524288 floats per b

// ---------------------------------------------------------------------------
// K1: fused encoders (k & q) + V projection. 8 rows/block, 256 blocks.
// Writes kr,ki,qr,qi [N,K] and V [N,D], all fp32.
__global__ __launch_bounds__(256) void encv_kernel(
    const float* __restrict__ x,
    const float* __restrict__ pos_k, const float* __restrict__ w1_k,
    const float* __restrict__ b1_k, const float* __restrict__ w2_k,
    const float* __restrict__ b2_k, const float* __restrict__ wa_k,
    const float* __restrict__ ba_k,
    const float* __restrict__ pos_q, const float* __restrict__ w1_q,
    const float* __restrict__ b1_q, const float* __restrict__ w2_q,
    const float* __restrict__ b2_q, const float* __restrict__ wa_q,
    const float* __restrict__ ba_q,
    const float* __restrict__ wv, const float* __restrict__ bv,
    float* __restrict__ kr, float* __restrict__ ki,
    float* __restrict__ qr, float* __restrict__ qi,
    float* __restrict__ V) {
  __shared__ float xs[ROWS][D];
  __shared__ float xak[ROWS][D];
  __shared__ float xaq[ROWS][D];
  __shared__ float hk[ROWS][D];
  __shared__ float hq[ROWS][D];
  __shared__ float phk[ROWS][K], amk[ROWS][K], phq[ROWS][K], amq[ROWS][K];
  const int tid = threadIdx.x;
  const int row0 = blockIdx.x * ROWS;

#pragma unroll
  for (int r = 0; r < ROWS; ++r) {
    const int row = row0 + r, l = row & (L - 1);
    const float xv = x[row * D + tid];
    xs[r][tid] = xv;
    xak[r][tid] = xv + pos_k[l * D + tid];
    xaq[r][tid] = xv + pos_q[l * D + tid];
  }
  __syncthreads();

  // Three D-wide GEMVs in one pass: h_k, h_q, V
  {
    float ak[ROWS], aq[ROWS], av[ROWS];
    const float bk = b1_k[tid], bq = b1_q[tid], bvv = bv[tid];
#pragma unroll
    for (int r = 0; r < ROWS; ++r) { ak[r] = bk; aq[r] = bq; av[r] = bvv; }
    for (int d = 0; d < D; ++d) {
      const float wk = w1_k[d * D + tid];
      const float wq = w1_q[d * D + tid];
      const float wvv = wv[d * D + tid];
#pragma unroll
      for (int r = 0; r < ROWS; ++r) {
        ak[r] += xak[r][d] * wk;
        aq[r] += xaq[r][d] * wq;
        av[r] += xs[r][d] * wvv;
      }
    }
#pragma unroll
    for (int r = 0; r < ROWS; ++r) {
      float v = ak[r];
      hk[r][tid] = 0.5f * v * (1.0f + erff(v * 0.70710678f));
      v = aq[r];
      hq[r][tid] = 0.5f * v * (1.0f + erff(v * 0.70710678f));
      V[(row0 + r) * D + tid] = av[r];
    }
  }
  __syncthreads();

  // Four 64-thread groups (= 4 waves): phase_k, amp_k, phase_q, amp_q
  {
    const int g = tid >> 6, j = tid & 63;
    float acc[ROWS];
    if (g == 0) {
      const float bb = b2_k[j];
#pragma unroll
      for (int r = 0; r < ROWS; ++r) acc[r] = bb;
      for (int d = 0; d < D; ++d) {
        const float w = w2_k[d * K + j];
#pragma unroll
        for (int r = 0; r < ROWS; ++r) acc[r] += hk[r][d] * w;
      }
#pragma unroll
      for (int r = 0; r < ROWS; ++r) phk[r][j] = tanhf(acc[r]) * 3.14159265358979f;
    } else if (g == 1) {
      const float bb = ba_k[j];
#pragma unroll
      for (int r = 0; r < ROWS; ++r) acc[r] = bb;
      for (int d = 0; d < D; ++d) {
        const float w = wa_k[d * K + j];
#pragma unroll
        for (int r = 0; r < ROWS; ++r) acc[r] += xak[r][d] * w;
      }
#pragma unroll
      for (int r = 0; r < ROWS; ++r) {
        const float v = acc[r];
        amk[r][j] = fmaxf(v, 0.0f) + log1pf(expf(-fabsf(v))) + 0.1f;
      }
    } else if (g == 2) {
      const float bb = b2_q[j];
#pragma unroll
      for (int r = 0; r < ROWS; ++r) acc[r] = bb;
      for (int d = 0; d < D; ++d) {
        const float w = w2_q[d * K + j];
#pragma unroll
        for (int r = 0; r < ROWS; ++r) acc[r] += hq[r][d] * w;
      }
#pragma unroll
      for (int r = 0; r < ROWS; ++r) phq[r][j] = tanhf(acc[r]) * 3.14159265358979f;
    } else {
      const float bb = ba_q[j];
#pragma unroll
      for (int r = 0; r < ROWS; ++r) acc[r] = bb;
      for (int d = 0; d < D; ++d) {
        const float w = wa_q[d * K + j];
#pragma unroll
        for (int r = 0; r < ROWS; ++r) acc[r] += xaq[r][d] * w;
      }
#pragma unroll
      for (int r = 0; r < ROWS; ++r) {
        const float v = acc[r];
        amq[r][j] = fmaxf(v, 0.0f) + log1pf(expf(-fabsf(v))) + 0.1f;
      }
    }
  }
  __syncthreads();

  for (int e = tid; e < ROWS * K; e += 256) {
    const int r = e >> 6, j = e & 63;
    const int row = row0 + r;
    const float akk = amk[r][j], pkk = phk[r][j];
    kr[row * K + j] = akk * cosf(pkk);
    ki[row * K + j] = akk * sinf(pkk);
    const float aqq = amq[r][j], pqq = phq[r][j];
    qr[row * K + j] = aqq * cosf(pqq);
    qi[row * K + j] = aqq * sinf(pqq);
  }
}

// ---------------------------------------------------------------------------
// K2: per-chunk outer-product sums T[b][c][comp][k][d] = sum_{t in chunk} kp*V.
// Grid (b,c,dchunk32) = 2*16*8 = 256 blocks.
__global__ __launch_bounds__(256) void tbuild_kernel(
    const float* __restrict__ kr, const float* __restrict__ ki,
    const float* __restrict__ V, float* __restrict__ TM) {
  const int id = blockIdx.x;
  const int dc = id & 7, c = (id >> 3) & 15, b = id >> 7;
  const int tid = threadIdx.x;
  const int n0 = b * L + c * 64;
  const int d = dc * 32 + (tid & 31);
  const int kb = tid >> 5;  // 0..7

  __shared__ float krL[64][65], kiL[64][65];
  for (int e = tid; e < 4096; e += 256) {
    const int t = e >> 6, k = e & 63;
    krL[t][k] = kr[(n0 + t) * K + k];
    kiL[t][k] = ki[(n0 + t) * K + k];
  }
  __syncthreads();

  float vcol[64];
#pragma unroll
  for (int t = 0; t < 64; ++t) vcol[t] = V[(n0 + t) * D + d];

  float ar[8], ai[8];
#pragma unroll
  for (int i = 0; i < 8; ++i) { ar[i] = 0.f; ai[i] = 0.f; }
#pragma unroll 4
  for (int t = 0; t < 64; ++t) {
    const float vt = vcol[t];
#pragma unroll
    for (int i = 0; i < 8; ++i) {
      const int k = kb * 8 + i;
      ar[i] += krL[t][k] * vt;
      ai[i] += kiL[t][k] * vt;
    }
  }

  const size_t base = (size_t)b * TM_BSTRIDE + (size_t)c * TM_CSTRIDE;
#pragma unroll
  for (int i = 0; i < 8; ++i) {
    const int k = kb * 8 + i;
    TM[base + (size_t)k * D + d] = ar[i];             // comp 0 (real)
    TM[base + (size_t)(K + k) * D + d] = ai[i];       // comp 1 (imag)
  }
}

// ---------------------------------------------------------------------------
// K3: in-place exclusive prefix over c: M[c] = sum_{c'<c} T[c'].
// 65536 columns, 256 blocks x 256 threads.
__global__ __launch_bounds__(256) void scan_kernel(float* __restrict__ TM) {
  const int col = blockIdx.x * 256 + threadIdx.x;
  const int d = col & 255;
  const int k = (col >> 8) & 63;
  const int comp = (col >> 14) & 1;
  const int b = col >> 15;
  size_t idx = (size_t)b * TM_BSTRIDE + (size_t)comp * (K * D) + (size_t)k * D + d;
  float run = 0.f;
#pragma unroll
  for (int c = 0; c < NC; ++c, idx += TM_CSTRIDE) {
    const float t = TM[idx];
    TM[idx] = run;
    run += t;
  }
}

// ---------------------------------------------------------------------------
// K4: fused retrieval + norm + layernorm + output projection + residual.
// 4 rows/block, 512 blocks.
__global__ __launch_bounds__(256) void out_kernel(
    const float* __restrict__ qr, const float* __restrict__ qi,
    const float* __restrict__ kr, const float* __restrict__ ki,
    const float* __restrict__ V, const float* __restrict__ TM,
    const float* __restrict__ x,
    const float* __restrict__ ln_g, const float* __restrict__ ln_b,
    const float* __restrict__ wo, const float* __restrict__ bo,
    float* __restrict__ out) {
  const int tid = threadIdx.x;
  const int r0 = blockIdx.x * 4;           // global row base
  const int b = r0 >> 10;
  const int l0 = r0 & (L - 1);
  const int c = l0 >> 6;                   // chunk index
  const int lo = l0 & 63;                  // offset within chunk (mult of 4)
  const int n0 = b * L + c * 64;           // chunk base row

  __shared__ float qrL[4][K], qiL[4][K];
  __shared__ float krL[64][65], kiL[64][65];
  __shared__ float SL[4][65];
  __shared__ float rn[4][D];
  __shared__ float red[4][2][4];           // [row][sum|sumsq][wave]

  {
    const int r = tid >> 6, k = tid & 63;  // exactly 4*64 = 256
    qrL[r][k] = qr[(r0 + r) * K + k];
    qiL[r][k] = qi[(r0 + r) * K + k];
  }
  for (int e = tid; e < 4096; e += 256) {
    const int t = e >> 6, k = e & 63;
    krL[t][k] = kr[(n0 + t) * K + k];
    kiL[t][k] = ki[(n0 + t) * K + k];
  }
  __syncthreads();

  // intra-chunk scores S_loc[row][t] = Re(conj(q_row) . kp_t), causal-masked
  {
    const int rq = tid >> 6, t = tid & 63;
    float s = 0.f;
#pragma unroll 8
    for (int k = 0; k < K; ++k)
      s += qrL[rq][k] * krL[t][k] + qiL[rq][k] * kiL[t][k];
    SL[rq][t] = (t <= lo + rq) ? s : 0.f;
  }
  __syncthreads();

  // main term: Re(conj(q) . M[c])  +  intra-chunk S_loc . V
  float accv[4] = {0.f, 0.f, 0.f, 0.f};
  const float* Mr = TM + (size_t)b * TM_BSTRIDE + (size_t)c * TM_CSTRIDE;
  const float* Mi = Mr + K * D;
#pragma unroll 4
  for (int k = 0; k < K; ++k) {
    const float mr = Mr[(size_t)k * D + tid];
    const float mi = Mi[(size_t)k * D + tid];
#pragma unroll
    for (int rq = 0; rq < 4; ++rq)
      accv[rq] += qrL[rq][k] * mr + qiL[rq][k] * mi;
  }
  const int tmax = lo + 3;  // block-uniform
  for (int t = 0; t <= tmax; ++t) {
    const float vt = V[(n0 + t) * D + tid];
#pragma unroll
    for (int rq = 0; rq < 4; ++rq) accv[rq] += SL[rq][t] * vt;
  }

  // normalize + LN statistics
  float val[4];
#pragma unroll
  for (int rq = 0; rq < 4; ++rq) {
    const int l = l0 + rq;
    val[rq] = accv[rq] * rsqrtf((float)(l + 1) * 64.0f);
  }
  const int w = tid >> 6;
#pragma unroll
  for (int rq = 0; rq < 4; ++rq) {
    float v = val[rq], v2 = v * v;
    for (int off = 32; off > 0; off >>= 1) {
      v += __shfl_xor(v, off, 64);
      v2 += __shfl_xor(v2, off, 64);
    }
    if ((tid & 63) == 0) { red[rq][0][w] = v; red[rq][1][w] = v2; }
  }
  __syncthreads();

  const float g = ln_g[tid], bb = ln_b[tid];
#pragma unroll
  for (int rq = 0; rq < 4; ++rq) {
    const float s = red[rq][0][0] + red[rq][0][1] + red[rq][0][2] + red[rq][0][3];
    const float sq = red[rq][1][0] + red[rq][1][1] + red[rq][1][2] + red[rq][1][3];
    const float mu = s * (1.0f / 256.0f);
    const float var = sq * (1.0f / 256.0f) - mu * mu;
    rn[rq][tid] = (val[rq] - mu) * rsqrtf(var + 1e-5f) * g + bb;
  }
  __syncthreads();

  // out = x + rn @ wo + bo
  float ao[4];
  const float bo_ = bo[tid];
#pragma unroll
  for (int rq = 0; rq < 4; ++rq) ao[rq] = bo_;
  for (int dd = 0; dd < D; ++dd) {
    const float wv_ = wo[dd * D + tid];
#pragma unroll
    for (int rq = 0; rq < 4; ++rq) ao[rq] += rn[rq][dd] * wv_;
  }
#pragma unroll
  for (int rq = 0; rq < 4; ++rq)
    out[(r0 + rq) * D + tid] = x[(r0 + rq) * D + tid] + ao[rq];
}

// ---------------------------------------------------------------------------
extern "C" void kernel_launch(void* const* d_in, const int* in_sizes, int n_in,
                              void* d_out, int out_size, void* d_ws, size_t ws_size,
                              hipStream_t stream) {
  (void)in_sizes; (void)n_in; (void)out_size; (void)ws_size;
  const float* x    = (const float*)d_in[0];
  const float* pos_k= (const float*)d_in[1];
  const float* w1_k = (const float*)d_in[2];
  const float* b1_k = (const float*)d_in[3];
  const float* w2_k = (const float*)d_in[4];
  const float* b2_k = (const float*)d_in[5];
  const float* wa_k = (const float*)d_in[6];
  const float* ba_k = (const float*)d_in[7];
  const float* pos_q= (const float*)d_in[8];
  const float* w1_q = (const float*)d_in[9];
  const float* b1_q = (const float*)d_in[10];
  const float* w2_q = (const float*)d_in[11];
  const float* b2_q = (const float*)d_in[12];
  const float* wa_q = (const float*)d_in[13];
  const float* ba_q = (const float*)d_in[14];
  const float* wv   = (const float*)d_in[15];
  const float* bv   = (const float*)d_in[16];
  const float* ln_g = (const float*)d_in[17];
  const float* ln_b = (const float*)d_in[18];
  const float* wo   = (const float*)d_in[19];
  const float* bo   = (const float*)d_in[20];

  float* ws = (float*)d_ws;
  float* kr = ws;                          // N*K
  float* ki = kr + (size_t)N * K;
  float* qr = ki + (size_t)N * K;
  float* qi = qr + (size_t)N * K;
  float* V  = qi + (size_t)N * K;          // N*D
  float* TM = V + (size_t)N * D;           // B*NC*2*K*D = 1M floats (4 MB)

  encv_kernel<<<N / ROWS, 256, 0, stream>>>(
      x, pos_k, w1_k, b1_k, w2_k, b2_k, wa_k, ba_k,
      pos_q, w1_q, b1_q, w2_q, b2_q, wa_q, ba_q, wv, bv,
      kr, ki, qr, qi, V);
  tbuild_kernel<<<B * NC * 8, 256, 0, stream>>>(kr, ki, V, TM);
  scan_kernel<<<(B * 2 * K * D) / 256, 256, 0, stream>>>(TM);
  out_kernel<<<N / 4, 256, 0, stream>>>(qr, qi, kr, ki, V, TM, x,
                                        ln_g, ln_b, wo, bo, (float*)d_out);
}

// Round 5
// 195.740 us; speedup vs baseline: 1.5727x; 1.0843x over previous
//
#include <hip/hip_runtime.h>
#include <hip/hip_bf16.h>

constexpr int B = 2, L = 1024, D = 256, K = 64;
constexpr int N = B * L;          // 2048 rows
constexpr int NC = L / 64;        // 16 chunks of 64 tokens
constexpr int TM_CSTRIDE = 2 * K * D;         // 32768 floats per (b,c)
constexpr int TM_BSTRIDE = NC * TM_CSTRIDE;   // 524288 floats per b

// ---------------------------------------------------------------------------
// K1: fused encoders (k & q) + V projection. 4 rows/block, 512 blocks.
__global__ __launch_bounds__(256) void encv_kernel(
    const float* __restrict__ x,
    const float* __restrict__ pos_k, const float* __restrict__ w1_k,
    const float* __restrict__ b1_k, const float* __restrict__ w2_k,
    const float* __restrict__ b2_k, const float* __restrict__ wa_k,
    const float* __restrict__ ba_k,
    const float* __restrict__ pos_q, const float* __restrict__ w1_q,
    const float* __restrict__ b1_q, const float* __restrict__ w2_q,
    const float* __restrict__ b2_q, const float* __restrict__ wa_q,
    const float* __restrict__ ba_q,
    const float* __restrict__ wv, const float* __restrict__ bv,
    float* __restrict__ kr, float* __restrict__ ki,
    float* __restrict__ qr, float* __restrict__ qi,
    float* __restrict__ V) {
  __shared__ float xs[4][D], xak[4][D], xaq[4][D], hk[4][D], hq[4][D];
  __shared__ float phk[4][K], amk[4][K], phq[4][K], amq[4][K];
  const int tid = threadIdx.x;
  const int row0 = blockIdx.x * 4;
  const int l0 = row0 & (L - 1);

  // stage x, x+pos_k, x+pos_q (float4; 4 rows x 64 float4 = 256 threads)
  {
    const int r = tid >> 6, d4 = (tid & 63) * 4;
    const int row = row0 + r, l = l0 + r;
    const float4 xv = *(const float4*)&x[row * D + d4];
    const float4 pk = *(const float4*)&pos_k[l * D + d4];
    const float4 pq = *(const float4*)&pos_q[l * D + d4];
    *(float4*)&xs[r][d4] = xv;
    float4 t1; t1.x = xv.x + pk.x; t1.y = xv.y + pk.y; t1.z = xv.z + pk.z; t1.w = xv.w + pk.w;
    *(float4*)&xak[r][d4] = t1;
    float4 t2; t2.x = xv.x + pq.x; t2.y = xv.y + pq.y; t2.z = xv.z + pq.z; t2.w = xv.w + pq.w;
    *(float4*)&xaq[r][d4] = t2;
  }
  __syncthreads();

  // three D-wide GEMVs in one pass: h_k, h_q, V  (d unrolled x4, b128 LDS reads)
  {
    float ak[4], aq[4], av[4];
    const float bk = b1_k[tid], bq = b1_q[tid], bvv = bv[tid];
#pragma unroll
    for (int r = 0; r < 4; ++r) { ak[r] = bk; aq[r] = bq; av[r] = bvv; }
    for (int d4 = 0; d4 < D; d4 += 4) {
      float wk[4], wq[4], wvv[4];
#pragma unroll
      for (int j = 0; j < 4; ++j) {
        wk[j] = w1_k[(d4 + j) * D + tid];
        wq[j] = w1_q[(d4 + j) * D + tid];
        wvv[j] = wv[(d4 + j) * D + tid];
      }
#pragma unroll
      for (int r = 0; r < 4; ++r) {
        const float4 a1 = *(const float4*)&xak[r][d4];
        const float4 a2 = *(const float4*)&xaq[r][d4];
        const float4 a3 = *(const float4*)&xs[r][d4];
        ak[r] += a1.x * wk[0] + a1.y * wk[1] + a1.z * wk[2] + a1.w * wk[3];
        aq[r] += a2.x * wq[0] + a2.y * wq[1] + a2.z * wq[2] + a2.w * wq[3];
        av[r] += a3.x * wvv[0] + a3.y * wvv[1] + a3.z * wvv[2] + a3.w * wvv[3];
      }
    }
#pragma unroll
    for (int r = 0; r < 4; ++r) {
      float v = ak[r];
      hk[r][tid] = 0.5f * v * (1.0f + erff(v * 0.70710678f));
      v = aq[r];
      hq[r][tid] = 0.5f * v * (1.0f + erff(v * 0.70710678f));
      V[(row0 + r) * D + tid] = av[r];
    }
  }
  __syncthreads();

  // four 64-thread groups: phase_k, amp_k, phase_q, amp_q
  {
    const int g = tid >> 6, j = tid & 63;
    const float* Wm = (g == 0) ? w2_k : (g == 1) ? wa_k : (g == 2) ? w2_q : wa_q;
    const float* bm = (g == 0) ? b2_k : (g == 1) ? ba_k : (g == 2) ? b2_q : ba_q;
    const float (*Am)[D] = (g == 0) ? hk : (g == 1) ? xak : (g == 2) ? hq : xaq;
    float acc[4];
    const float bb = bm[j];
#pragma unroll
    for (int r = 0; r < 4; ++r) acc[r] = bb;
    for (int d4 = 0; d4 < D; d4 += 4) {
      float wj[4];
#pragma unroll
      for (int jj = 0; jj < 4; ++jj) wj[jj] = Wm[(d4 + jj) * K + j];
#pragma unroll
      for (int r = 0; r < 4; ++r) {
        const float4 a = *(const float4*)&Am[r][d4];
        acc[r] += a.x * wj[0] + a.y * wj[1] + a.z * wj[2] + a.w * wj[3];
      }
    }
    if (g == 0 || g == 2) {
      float (*ph)[K] = (g == 0) ? phk : phq;
#pragma unroll
      for (int r = 0; r < 4; ++r) ph[r][j] = tanhf(acc[r]) * 3.14159265358979f;
    } else {
      float (*am)[K] = (g == 1) ? amk : amq;
#pragma unroll
      for (int r = 0; r < 4; ++r) {
        const float v = acc[r];
        am[r][j] = fmaxf(v, 0.0f) + log1pf(expf(-fabsf(v))) + 0.1f;
      }
    }
  }
  __syncthreads();

  {
    const int r = tid >> 6, j = tid & 63;   // 4*64 = 256 exactly
    const int row = row0 + r;
    const float akk = amk[r][j], pkk = phk[r][j];
    kr[row * K + j] = akk * cosf(pkk);
    ki[row * K + j] = akk * sinf(pkk);
    const float aqq = amq[r][j], pqq = phq[r][j];
    qr[row * K + j] = aqq * cosf(pqq);
    qi[row * K + j] = aqq * sinf(pqq);
  }
}

// ---------------------------------------------------------------------------
// K2: per-chunk outer-product sums T[b][c][comp][k][d]. Grid (b,c,dc16)=512.
__global__ __launch_bounds__(256) void tbuild_kernel(
    const float* __restrict__ kr, const float* __restrict__ ki,
    const float* __restrict__ V, float* __restrict__ TM) {
  const int id = blockIdx.x;
  const int dc = id & 15, c = (id >> 4) & 15, b = id >> 8;
  const int tid = threadIdx.x;
  const int n0 = b * L + c * 64;
  const int d = dc * 16 + (tid & 15);
  const int kb = tid >> 4;  // 0..15, owns k = kb*4 .. kb*4+3

  __shared__ float krL[64][68], kiL[64][68];   // stride 68 => b128-aligned rows
  for (int e = tid; e < 1024; e += 256) {
    const int t = e >> 4, k4 = (e & 15) * 4;
    *(float4*)&krL[t][k4] = *(const float4*)&kr[(n0 + t) * K + k4];
    *(float4*)&kiL[t][k4] = *(const float4*)&ki[(n0 + t) * K + k4];
  }
  __syncthreads();

  float vcol[64];
#pragma unroll 8
  for (int t = 0; t < 64; ++t) vcol[t] = V[(n0 + t) * D + d];

  float ar[4] = {0.f, 0.f, 0.f, 0.f}, ai[4] = {0.f, 0.f, 0.f, 0.f};
#pragma unroll 4
  for (int t = 0; t < 64; ++t) {
    const float vt = vcol[t];
    const float4 k4r = *(const float4*)&krL[t][kb * 4];
    const float4 k4i = *(const float4*)&kiL[t][kb * 4];
    ar[0] += k4r.x * vt; ar[1] += k4r.y * vt; ar[2] += k4r.z * vt; ar[3] += k4r.w * vt;
    ai[0] += k4i.x * vt; ai[1] += k4i.y * vt; ai[2] += k4i.z * vt; ai[3] += k4i.w * vt;
  }

  const size_t base = (size_t)b * TM_BSTRIDE + (size_t)c * TM_CSTRIDE;
#pragma unroll
  for (int i = 0; i < 4; ++i) {
    const int k = kb * 4 + i;
    TM[base + (size_t)k * D + d] = ar[i];
    TM[base + (size_t)(K + k) * D + d] = ai[i];
  }
}

// ---------------------------------------------------------------------------
// K3: in-place exclusive prefix over c.
__global__ __launch_bounds__(256) void scan_kernel(float* __restrict__ TM) {
  const int col = blockIdx.x * 256 + threadIdx.x;
  const int d = col & 255;
  const int k = (col >> 8) & 63;
  const int comp = (col >> 14) & 1;
  const int b = col >> 15;
  size_t idx = (size_t)b * TM_BSTRIDE + (size_t)comp * (K * D) + (size_t)k * D + d;
  float run = 0.f;
#pragma unroll
  for (int c = 0; c < NC; ++c, idx += TM_CSTRIDE) {
    const float t = TM[idx];
    TM[idx] = run;
    run += t;
  }
}

// ---------------------------------------------------------------------------
// K4: fused retrieval + norm + LN + output projection + residual.
// 2 rows/block, 1024 blocks.
__global__ __launch_bounds__(256) void out_kernel(
    const float* __restrict__ qr, const float* __restrict__ qi,
    const float* __restrict__ kr, const float* __restrict__ ki,
    const float* __restrict__ V, const float* __restrict__ TM,
    const float* __restrict__ x,
    const float* __restrict__ ln_g, const float* __restrict__ ln_b,
    const float* __restrict__ wo, const float* __restrict__ bo,
    float* __restrict__ out) {
  const int tid = threadIdx.x;
  const int r0 = blockIdx.x * 2;
  const int b = r0 >> 10;
  const int l0 = r0 & (L - 1);
  const int c = l0 >> 6;
  const int lo = l0 & 63;                  // even, 0..62
  const int n0 = b * L + c * 64;
  const int nrows = lo + 2;                // K-rows needed (t <= lo+1)

  __shared__ float qrL[2][K], qiL[2][K];
  __shared__ float krL[64][68], kiL[64][68];
  __shared__ float SL[2][64];
  __shared__ float rn[2][D];
  __shared__ float red[2][2][4];

  if (tid < 128) {
    const int r = tid >> 6, k = tid & 63;
    qrL[r][k] = qr[(r0 + r) * K + k];
    qiL[r][k] = qi[(r0 + r) * K + k];
  }
  for (int e = tid; e < nrows * 16; e += 256) {
    const int t = e >> 4, k4 = (e & 15) * 4;
    *(float4*)&krL[t][k4] = *(const float4*)&kr[(n0 + t) * K + k4];
    *(float4*)&kiL[t][k4] = *(const float4*)&ki[(n0 + t) * K + k4];
  }
  __syncthreads();

  // intra-chunk scores (only t <= lo+rq nonzero)
  if (tid < 128) {
    const int rq = tid >> 6, t = tid & 63;
    float s = 0.f;
    if (t <= lo + rq) {
#pragma unroll
      for (int k4 = 0; k4 < K; k4 += 4) {
        const float4 a = *(const float4*)&qrL[rq][k4];
        const float4 bb = *(const float4*)&qiL[rq][k4];
        const float4 kk = *(const float4*)&krL[t][k4];
        const float4 kki = *(const float4*)&kiL[t][k4];
        s += a.x * kk.x + a.y * kk.y + a.z * kk.z + a.w * kk.w +
             bb.x * kki.x + bb.y * kki.y + bb.z * kki.z + bb.w * kki.w;
      }
    }
    SL[rq][t] = s;
  }
  __syncthreads();

  // main term: Re(conj(q) . M[c]) + intra-chunk S_loc . V   (column = tid)
  float acc0 = 0.f, acc1 = 0.f;
  const float* Mr = TM + (size_t)b * TM_BSTRIDE + (size_t)c * TM_CSTRIDE;
  const float* Mi = Mr + K * D;
  for (int k4 = 0; k4 < K; k4 += 4) {
    const float4 q0r = *(const float4*)&qrL[0][k4];
    const float4 q0i = *(const float4*)&qiL[0][k4];
    const float4 q1r = *(const float4*)&qrL[1][k4];
    const float4 q1i = *(const float4*)&qiL[1][k4];
#pragma unroll
    for (int j = 0; j < 4; ++j) {
      const float mr = Mr[(size_t)(k4 + j) * D + tid];
      const float mi = Mi[(size_t)(k4 + j) * D + tid];
      acc0 += ((const float*)&q0r)[j] * mr + ((const float*)&q0i)[j] * mi;
      acc1 += ((const float*)&q1r)[j] * mr + ((const float*)&q1i)[j] * mi;
    }
  }
  {
    const int tmax = lo + 1;
    for (int t = 0; t <= tmax; ++t) {
      const float vt = V[(n0 + t) * D + tid];
      acc0 += SL[0][t] * vt;
      acc1 += SL[1][t] * vt;
    }
  }

  // normalize + LN
  float val[2];
  val[0] = acc0 * rsqrtf((float)(l0 + 1) * 64.0f);
  val[1] = acc1 * rsqrtf((float)(l0 + 2) * 64.0f);
  const int w = tid >> 6;
#pragma unroll
  for (int rq = 0; rq < 2; ++rq) {
    float v = val[rq], v2 = v * v;
    for (int off = 32; off > 0; off >>= 1) {
      v += __shfl_xor(v, off, 64);
      v2 += __shfl_xor(v2, off, 64);
    }
    if ((tid & 63) == 0) { red[rq][0][w] = v; red[rq][1][w] = v2; }
  }
  __syncthreads();

  const float g = ln_g[tid], bb = ln_b[tid];
#pragma unroll
  for (int rq = 0; rq < 2; ++rq) {
    const float s = red[rq][0][0] + red[rq][0][1] + red[rq][0][2] + red[rq][0][3];
    const float sq = red[rq][1][0] + red[rq][1][1] + red[rq][1][2] + red[rq][1][3];
    const float mu = s * (1.0f / 256.0f);
    const float var = sq * (1.0f / 256.0f) - mu * mu;
    rn[rq][tid] = (val[rq] - mu) * rsqrtf(var + 1e-5f) * g + bb;
  }
  __syncthreads();

  // out = x + rn @ wo + bo
  float ao0, ao1;
  ao0 = ao1 = bo[tid];
  for (int d4 = 0; d4 < D; d4 += 4) {
    float wj[4];
#pragma unroll
    for (int j = 0; j < 4; ++j) wj[j] = wo[(d4 + j) * D + tid];
    const float4 r0v = *(const float4*)&rn[0][d4];
    const float4 r1v = *(const float4*)&rn[1][d4];
    ao0 += r0v.x * wj[0] + r0v.y * wj[1] + r0v.z * wj[2] + r0v.w * wj[3];
    ao1 += r1v.x * wj[0] + r1v.y * wj[1] + r1v.z * wj[2] + r1v.w * wj[3];
  }
  out[(r0 + 0) * D + tid] = x[(r0 + 0) * D + tid] + ao0;
  out[(r0 + 1) * D + tid] = x[(r0 + 1) * D + tid] + ao1;
}

// ---------------------------------------------------------------------------
extern "C" void kernel_launch(void* const* d_in, const int* in_sizes, int n_in,
                              void* d_out, int out_size, void* d_ws, size_t ws_size,
                              hipStream_t stream) {
  (void)in_sizes; (void)n_in; (void)out_size; (void)ws_size;
  const float* x    = (const float*)d_in[0];
  const float* pos_k= (const float*)d_in[1];
  const float* w1_k = (const float*)d_in[2];
  const float* b1_k = (const float*)d_in[3];
  const float* w2_k = (const float*)d_in[4];
  const float* b2_k = (const float*)d_in[5];
  const float* wa_k = (const float*)d_in[6];
  const float* ba_k = (const float*)d_in[7];
  const float* pos_q= (const float*)d_in[8];
  const float* w1_q = (const float*)d_in[9];
  const float* b1_q = (const float*)d_in[10];
  const float* w2_q = (const float*)d_in[11];
  const float* b2_q = (const float*)d_in[12];
  const float* wa_q = (const float*)d_in[13];
  const float* ba_q = (const float*)d_in[14];
  const float* wv   = (const float*)d_in[15];
  const float* bv   = (const float*)d_in[16];
  const float* ln_g = (const float*)d_in[17];
  const float* ln_b = (const float*)d_in[18];
  const float* wo   = (const float*)d_in[19];
  const float* bo   = (const float*)d_in[20];

  float* ws = (float*)d_ws;
  float* kr = ws;                          // N*K
  float* ki = kr + (size_t)N * K;
  float* qr = ki + (size_t)N * K;
  float* qi = qr + (size_t)N * K;
  float* V  = qi + (size_t)N * K;          // N*D
  float* TM = V + (size_t)N * D;           // B*NC*2*K*D floats (4 MB)

  encv_kernel<<<N / 4, 256, 0, stream>>>(
      x, pos_k, w1_k, b1_k, w2_k, b2_k, wa_k, ba_k,
      pos_q, w1_q, b1_q, w2_q, b2_q, wa_q, ba_q, wv, bv,
      kr, ki, qr, qi, V);
  tbuild_kernel<<<B * NC * 16, 256, 0, stream>>>(kr, ki, V, TM);
  scan_kernel<<<(B * 2 * K * D) / 256, 256, 0, stream>>>(TM);
  out_kernel<<<N / 2, 256, 0, stream>>>(qr, qi, kr, ki, V, TM, x,
                                        ln_g, ln_b, wo, bo, (float*)d_out);
}